// Round 7
// baseline (188.967 us; speedup 1.0000x reference)
//
#include <hip/hip_runtime.h>

// CasualSelfAttention fused block for MI355X (gfx950).
// B=4, T=2048, C=1024, H=16, D=64.
// x->bf16 conv -> weight transpose+conv -> 256x256 8-phase QKV GEMM (Q pre-scaled,
// V written transposed) -> 32x32-MFMA flash attention (in-register softmax via
// cvt_pk + permlane32_swap, K/V double-buffer, 1 barrier/iter) -> 256x128 proj GEMM.
// Workspace (75,497,472 B):
//   [0,        33554432)  qk  bf16 [B,T,2C]      (Q cols 0..1023 pre-scaled, K cols 1024..2047)
//   [33554432, 50331648)  vT  bf16 [B*H][64][T]
//   [50331648, 67108864)  xbf bf16 [B,T,C]  (QKV phase)  /  attn bf16 [B,T,C] (flash+proj phase)
//   [67108864, 73400320)  w_attn^T bf16 [3C][C]
//   [73400320, 75497472)  w_proj^T bf16 [C][C]

using u16 = unsigned short;
using u32 = unsigned int;
using bf16x8 = __attribute__((ext_vector_type(8))) __bf16;
using f32x4  = __attribute__((ext_vector_type(4))) float;
using f32x16 = __attribute__((ext_vector_type(16))) float;
using u16x8  = __attribute__((ext_vector_type(8))) u16;
using u16x4  = __attribute__((ext_vector_type(4))) u16;
using u32x2  = __attribute__((ext_vector_type(2))) u32;
using u32x4  = __attribute__((ext_vector_type(4))) u32;
using fvec4  = __attribute__((ext_vector_type(4))) float;

__device__ __forceinline__ u16 f2bf(float f) {
  u32 u = __builtin_bit_cast(u32, f);
  u32 r = (u + 0x7FFFu + ((u >> 16) & 1u)) >> 16;
  return (u16)r;
}

__device__ __forceinline__ u32 cvtpk(float lo, float hi) {
  u32 r;
  asm("v_cvt_pk_bf16_f32 %0, %1, %2" : "=v"(r) : "v"(lo), "v"(hi));
  return r;
}

__device__ __forceinline__ f32x4 mfma16(bf16x8 a, bf16x8 b, f32x4 c) {
  return __builtin_amdgcn_mfma_f32_16x16x32_bf16(a, b, c, 0, 0, 0);
}

__device__ __forceinline__ f32x16 mfma32(bf16x8 a, bf16x8 b, f32x16 c) {
  return __builtin_amdgcn_mfma_f32_32x32x16_bf16(a, b, c, 0, 0, 0);
}

__device__ __forceinline__ void gld16(const u16* g, u16* l) {
  __builtin_amdgcn_global_load_lds(
      (const __attribute__((address_space(1))) void*)g,
      (__attribute__((address_space(3))) void*)l, 16, 0, 0);
}

// lgkm-only workgroup barrier: does NOT drain vmcnt
__device__ __forceinline__ void lgkm_barrier() {
  asm volatile("s_waitcnt lgkmcnt(0)" ::: "memory");
  __builtin_amdgcn_s_barrier();
  __builtin_amdgcn_sched_barrier(0);
}

// ---------------- f32 -> bf16 bulk convert ----------------
__global__ __launch_bounds__(256) void conv_kernel(
    const float* __restrict__ in, u16* __restrict__ out) {
  const size_t i = ((size_t)blockIdx.x * 256 + threadIdx.x) * 8;
  fvec4 a = *(const fvec4*)(in + i);
  fvec4 b = *(const fvec4*)(in + i + 4);
  u16x8 h;
#pragma unroll
  for (int j = 0; j < 4; ++j) { h[j] = f2bf(a[j]); h[4 + j] = f2bf(b[j]); }
  *(u16x8*)(out + i) = h;
}

// ---------------- transpose + f32->bf16 convert: W[K][N] -> Wt[N][K] ----------------
__global__ __launch_bounds__(256) void transpose_conv_kernel(
    const float* __restrict__ W, u16* __restrict__ Wt, int K, int N) {
  __shared__ float tile[32][33];
  const int n0 = blockIdx.x * 32, k0 = blockIdx.y * 32;
  const int tx = threadIdx.x, ty = threadIdx.y;  // 32 x 8
#pragma unroll
  for (int j = 0; j < 4; ++j)
    tile[ty + j * 8][tx] = W[(size_t)(k0 + ty + j * 8) * N + n0 + tx];
  __syncthreads();
#pragma unroll
  for (int j = 0; j < 4; ++j)
    Wt[(size_t)(n0 + ty + j * 8) * K + k0 + tx] = f2bf(tile[tx][ty + j * 8]);
}

// ---------------- 256xBN x64 8-phase bf16 GEMM ----------------
// NB = N-fragments per wave (4 -> BN=256, 2 -> BN=128). 512 threads = 8 waves (2M x NBc).
// Per K-tile: 4 phases; each stages one K-slice tile of tile t+1; counted vmcnt(2+NB/2).
template <int NB, bool QKV>
__global__ __launch_bounds__(512, 2) void gemm256_kernel(
    const u16* __restrict__ A, const u16* __restrict__ Bt,
    const float* __restrict__ bias, void* __restrict__ Cp,
    u16* __restrict__ vt, int M, int N, int K) {
  constexpr float SC = 0.18033688011112042f;  // 0.125 * log2(e)
  __shared__ u16 As[2][2][8192];
  __shared__ u16 Bs[2][2][NB * 2048];
  const int tid = threadIdx.x;
  const int l = tid & 63, w = tid >> 6;
  const int l15 = l & 15, l16 = l >> 4;
  const int wr = w >> 2, wc = w & 3;

  const u32 nwg = gridDim.x * gridDim.y;
  u32 f = blockIdx.y * gridDim.x + blockIdx.x;
  f = (f & 7) * (nwg >> 3) + (f >> 3);
  const int ntile = gridDim.x;
  const long mbase = (long)(f / ntile) * 256;
  const long nbase = (long)(f % ntile) * (NB * 64);

  const int raS0 = w * 16 + (l >> 2);
  const int raS1 = raS0 + 128;
  const int scS0 = ((l & 3) ^ ((raS0 >> 1) & 3)) * 8;
  const int scS1 = ((l & 3) ^ ((raS1 >> 1) & 3)) * 8;
  const u16* gA0 = A + (mbase + raS0) * (long)K + scS0;
  const u16* gA1 = A + (mbase + raS1) * (long)K + scS1;
  const u16* gB0 = Bt + (nbase + raS0) * (long)K + scS0;
  const u16* gB1 = Bt + (nbase + raS1) * (long)K + scS1;  // used only when NB==4

  const int raA = wr * 128 + l15;
  const int offA = raA * 32 + ((l16 ^ ((raA >> 1) & 3)) * 8);
  const int raB = wc * (NB * 16) + l15;
  const int offB = raB * 32 + ((l16 ^ ((raB >> 1) & 3)) * 8);

  f32x4 acc[8][NB] = {};
  bf16x8 af[4], bq[NB];
  const int NT = K >> 6;

#define STAGE_A(sb, ks, koff)                       \
  gld16(gA0 + (koff), &As[sb][ks][tid * 8]);        \
  gld16(gA1 + (koff), &As[sb][ks][tid * 8 + 4096]);

#define STAGE_B(sb, ks, koff)                                          \
  gld16(gB0 + (koff), &Bs[sb][ks][tid * 8]);                           \
  if constexpr (NB == 4) gld16(gB1 + (koff), &Bs[sb][ks][tid * 8 + 4096]);

#define DSA(cb, mh, ks)                                              \
  { _Pragma("unroll") for (int i_ = 0; i_ < 4; ++i_)                 \
      af[i_] = *(const bf16x8*)&As[cb][ks][offA + ((mh)*4 + i_) * 512]; }

#define DSB(cb, ks)                                                  \
  { _Pragma("unroll") for (int j_ = 0; j_ < NB; ++j_)                \
      bq[j_] = *(const bf16x8*)&Bs[cb][ks][offB + j_ * 512]; }

#define CLUSTER(mh)                                                            \
  __builtin_amdgcn_s_setprio(1);                                               \
  _Pragma("unroll") for (int i_ = 0; i_ < 4; ++i_)                             \
    _Pragma("unroll") for (int j_ = 0; j_ < NB; ++j_)                          \
      acc[(mh)*4 + i_][j_] = mfma16(af[i_], bq[j_], acc[(mh)*4 + i_][j_]);     \
  __builtin_amdgcn_s_setprio(0);

#define WAITVM()                                                         \
  if constexpr (NB == 4) { asm volatile("s_waitcnt vmcnt(4)" ::: "memory"); } \
  else { asm volatile("s_waitcnt vmcnt(3)" ::: "memory"); }

#define BAR_LGKM()                                        \
  __builtin_amdgcn_sched_barrier(0);                      \
  __builtin_amdgcn_s_barrier();                           \
  asm volatile("s_waitcnt lgkmcnt(0)" ::: "memory");      \
  __builtin_amdgcn_sched_barrier(0)

#define BAR_END()                     \
  __builtin_amdgcn_sched_barrier(0);  \
  __builtin_amdgcn_s_barrier()

  // prologue: stage all 4 K-slice tiles of K-tile 0
  STAGE_A(0, 0, 0);
  STAGE_B(0, 0, 0);
  STAGE_A(0, 1, 32);
  STAGE_B(0, 1, 32);
  WAITVM();
  __builtin_amdgcn_s_barrier();

  for (int t = 0; t < NT - 1; ++t) {
    const int cb = t & 1, sb = cb ^ 1;
    const long kn = (long)(t + 1) * 64;
    DSA(cb, 0, 0); DSB(cb, 0);
    STAGE_A(sb, 0, kn);
    BAR_LGKM();
    CLUSTER(0);
    BAR_END();
    DSA(cb, 1, 0);
    STAGE_B(sb, 0, kn);
    BAR_LGKM();
    CLUSTER(1);
    WAITVM();
    BAR_END();
    DSA(cb, 0, 1); DSB(cb, 1);
    STAGE_A(sb, 1, kn + 32);
    BAR_LGKM();
    CLUSTER(0);
    BAR_END();
    DSA(cb, 1, 1);
    STAGE_B(sb, 1, kn + 32);
    BAR_LGKM();
    CLUSTER(1);
    WAITVM();
    BAR_END();
  }
  {  // peeled last K-tile
    const int cb = (NT - 1) & 1;
    DSA(cb, 0, 0); DSB(cb, 0);
    BAR_LGKM();
    CLUSTER(0);
    BAR_END();
    DSA(cb, 1, 0);
    BAR_LGKM();
    CLUSTER(1);
    asm volatile("s_waitcnt vmcnt(0)" ::: "memory");
    BAR_END();
    DSA(cb, 0, 1); DSB(cb, 1);
    BAR_LGKM();
    CLUSTER(0);
    BAR_END();
    DSA(cb, 1, 1);
    BAR_LGKM();
    CLUSTER(1);
  }
#undef STAGE_A
#undef STAGE_B
#undef DSA
#undef DSB
#undef CLUSTER
#undef WAITVM
#undef BAR_LGKM
#undef BAR_END

  if constexpr (QKV) {
    const bool isv = (nbase >= 2048);
#pragma unroll
    for (int mi = 0; mi < 8; ++mi) {
#pragma unroll
      for (int ni = 0; ni < NB; ++ni) {
        const long m0 = mbase + wr * 128 + mi * 16 + l16 * 4;
        const int n = (int)nbase + wc * (NB * 16) + ni * 16 + l15;
        const float bv = bias[n];
        if (!isv) {
          u16* qkp = (u16*)Cp;
          const float sc = (n < 1024) ? SC : 1.0f;
#pragma unroll
          for (int r = 0; r < 4; ++r)
            qkp[(m0 + r) * 2048 + n] = f2bf((acc[mi][ni][r] + bv) * sc);
        } else {
          const int vc = n - 2048, hh = vc >> 6, dd = vc & 63;
          const int bb = (int)(m0 >> 11), t0 = (int)(m0 & 2047);
          u16x4 pk;
#pragma unroll
          for (int r = 0; r < 4; ++r) pk[r] = f2bf(acc[mi][ni][r] + bv);
          *(u16x4*)(vt + ((size_t)(bb * 16 + hh) * 64 + dd) * 2048 + t0) = pk;
        }
      }
    }
  } else {
#pragma unroll
    for (int mi = 0; mi < 8; ++mi) {
#pragma unroll
      for (int ni = 0; ni < NB; ++ni) {
        const long row0 = mbase + wr * 128 + mi * 16 + l16 * 4;
        const long col = nbase + wc * (NB * 16) + ni * 16 + l15;
        const float bv = bias[col];
#pragma unroll
        for (int r = 0; r < 4; ++r)
          ((float*)Cp)[(row0 + r) * (long)N + col] = acc[mi][ni][r] + bv;
      }
    }
  }
}

// ---------------- 32x32-MFMA flash attention, in-register softmax ----------------
// grid 512 (8 pairs x 64 bh); block = 4 waves x 32 q (QBLK=128); paired {p,15-p}: 34 iters.
// Swapped QK^T at 32x32: C col = q (lane&31), row = key crow(r,hi)=(r&3)+8*(r>>2)+4*hi.
// P redistribution to the PV B-fragment = 16 cvt_pk + 8 v_permlane32_swap (no LDS).
// K/V double-buffered (1 barrier/iter); fixed-shift softmax p=exp2(s-4).
__global__ __launch_bounds__(256, 2) void flash_kernel(
    const u16* __restrict__ qk, const u16* __restrict__ vt, u16* __restrict__ attn_out) {
  constexpr float MFIX = 4.0f;
  __shared__ u16 Ks[2][64 * 64];  // [buf][key][64 d], XOR-swizzled 128B rows
  __shared__ u16 Vs[2][64 * 64];  // [buf][d][64 key]
  const int tid = threadIdx.x;
  const int lane = tid & 63, w = tid >> 6;
  const int l31 = lane & 31, hi = lane >> 5;
  const int xorv = (l31 & 7) << 4;

  const u32 i = blockIdx.y * 8 + blockIdx.x;
  const int jj = i >> 3;
  const int bh = (i & 7) | ((jj & 7) << 3);
  const int pair = (int)(i >> 6);
  const int b = bh >> 4, h = bh & 15;
  const u16* qbase = qk + (size_t)b * 2048 * 2048 + h * 64;
  const u16* kbase = qbase + 1024;
  const u16* vbase = vt + (size_t)bh * 64 * 2048;
  u16* obase = attn_out + (size_t)b * 2048 * 1024 + h * 64;

  const int r0 = tid >> 3, c0 = (tid & 7) * 8;
  const int sco = ((c0 * 2) ^ ((r0 & 7) << 4)) >> 1;  // swizzled staging col (u16)

  int cur = 0;
  for (int half = 0; half < 2; ++half) {
    const int qt = half ? (15 - pair) : pair;
    const int nt = 2 * qt + 2;
    const int qr0 = qt * 128 + w * 32;
    const int q = qr0 + l31;

    // Q B-frags: col=q, k(d) = ds*16 + hi*8 + e
    bf16x8 qf[4];
#pragma unroll
    for (int ds = 0; ds < 4; ++ds)
      qf[ds] = *(const bf16x8*)(qbase + (size_t)q * 2048 + ds * 16 + hi * 8);

    f32x16 oacc[2] = {};
    float lsum = 0.f;

    u16x8 kreg[2], vreg[2];
    kreg[0] = *(const u16x8*)(kbase + (size_t)r0 * 2048 + c0);
    kreg[1] = *(const u16x8*)(kbase + (size_t)(r0 + 32) * 2048 + c0);
    vreg[0] = *(const u16x8*)(vbase + (size_t)r0 * 2048 + c0);
    vreg[1] = *(const u16x8*)(vbase + (size_t)(r0 + 32) * 2048 + c0);

    for (int kt = 0; kt < nt; ++kt) {
      const int kb = kt * 64;
      // stage into buf[cur] (other waves' reads of buf[cur^1] unaffected)
      *(u16x8*)(&Ks[cur][r0 * 64 + sco]) = kreg[0];
      *(u16x8*)(&Ks[cur][(r0 + 32) * 64 + sco]) = kreg[1];
      *(u16x8*)(&Vs[cur][r0 * 64 + sco]) = vreg[0];
      *(u16x8*)(&Vs[cur][(r0 + 32) * 64 + sco]) = vreg[1];
      lgkm_barrier();  // all writes visible; vmcnt NOT drained
      if (kt + 1 < nt) {  // prefetch next tile
        const int nb = kb + 64;
        kreg[0] = *(const u16x8*)(kbase + (size_t)(nb + r0) * 2048 + c0);
        kreg[1] = *(const u16x8*)(kbase + (size_t)(nb + r0 + 32) * 2048 + c0);
        vreg[0] = *(const u16x8*)(vbase + (size_t)r0 * 2048 + nb + c0);
        vreg[1] = *(const u16x8*)(vbase + (size_t)(r0 + 32) * 2048 + nb + c0);
      }

      // S^T = K Q^T (two 32-key halves), A = K rows from LDS
      f32x16 s0 = {}, s1 = {};
      __builtin_amdgcn_s_setprio(1);
#pragma unroll
      for (int ds = 0; ds < 4; ++ds) {
        const int col = (ds * 32 + hi * 16) ^ xorv;
        bf16x8 k0 = *(const bf16x8*)((const char*)&Ks[cur][0] + l31 * 128 + col);
        bf16x8 k1 = *(const bf16x8*)((const char*)&Ks[cur][0] + (32 + l31) * 128 + col);
        s0 = mfma32(k0, qf[ds], s0);
        s1 = mfma32(k1, qf[ds], s1);
      }
      __builtin_amdgcn_s_setprio(0);

      if (kb + 63 > qr0) {  // causal mask (tiles crossing this wave's diagonal)
#pragma unroll
        for (int r = 0; r < 16; ++r) {
          const int crow = (r & 3) + 8 * (r >> 2) + 4 * hi;
          if (kb + crow > q) s0[r] = -1e30f;
          if (kb + 32 + crow > q) s1[r] = -1e30f;
        }
      }

      // p = exp2(s - MFIX), per-lane lsum, pack to PV B-frags in-register
      float p0[16], p1[16];
      float ps = 0.f;
#pragma unroll
      for (int r = 0; r < 16; ++r) {
        p0[r] = exp2f(s0[r] - MFIX);
        p1[r] = exp2f(s1[r] - MFIX);
        ps += p0[r] + p1[r];
      }
      lsum += ps;

      bf16x8 pf[4];  // B-frag per 16-key slice: col=q, k=key (l>>5)*8+e
#pragma unroll
      for (int kh = 0; kh < 2; ++kh) {
#pragma unroll
        for (int c = 0; c < 2; ++c) {
          const float* pp = kh ? p1 : p0;
          const int bs = c * 8;
          u32 L0 = cvtpk(pp[bs + 0], pp[bs + 1]);
          u32 L1 = cvtpk(pp[bs + 2], pp[bs + 3]);
          u32 L2 = cvtpk(pp[bs + 4], pp[bs + 5]);
          u32 L3 = cvtpk(pp[bs + 6], pp[bs + 7]);
          asm("v_permlane32_swap_b32 %0, %1" : "+v"(L0), "+v"(L2));
          asm("v_permlane32_swap_b32 %0, %1" : "+v"(L1), "+v"(L3));
          u32x4 pk = {L0, L1, L2, L3};
          pf[kh * 2 + c] = __builtin_bit_cast(bf16x8, pk);
        }
      }

      // O^T += V^T P : A = V^T rows (d) from LDS, B = pf
      __builtin_amdgcn_s_setprio(1);
#pragma unroll
      for (int dh = 0; dh < 2; ++dh) {
#pragma unroll
        for (int ks = 0; ks < 4; ++ks) {
          const int col = (ks * 32 + hi * 16) ^ xorv;
          bf16x8 vf = *(const bf16x8*)((const char*)&Vs[cur][0] + (dh * 32 + l31) * 128 + col);
          oacc[dh] = mfma32(vf, pf[ks], oacc[dh]);
        }
      }
      __builtin_amdgcn_s_setprio(0);
      cur ^= 1;
    }

    // epilogue: full row-sum (partner holds other 32 keys), lane-local normalize
    lsum += __shfl_xor(lsum, 32);
    const float inv = 1.0f / lsum;
    u16* orow = obase + (size_t)q * 1024;
#pragma unroll
    for (int dh = 0; dh < 2; ++dh) {
#pragma unroll
      for (int jq = 0; jq < 4; ++jq) {  // d quad: dh*32 + 8*jq + 4*hi + 0..3
        u32x2 pk;
        pk[0] = cvtpk(oacc[dh][jq * 4 + 0] * inv, oacc[dh][jq * 4 + 1] * inv);
        pk[1] = cvtpk(oacc[dh][jq * 4 + 2] * inv, oacc[dh][jq * 4 + 3] * inv);
        *(u32x2*)(orow + dh * 32 + 8 * jq + 4 * hi) = pk;
      }
    }
  }
}

extern "C" void kernel_launch(void* const* d_in, const int* in_sizes, int n_in,
                              void* d_out, int out_size, void* d_ws, size_t ws_size,
                              hipStream_t stream) {
  (void)in_sizes; (void)n_in; (void)out_size; (void)ws_size;
  const float* x      = (const float*)d_in[0];  // [4,2048,1024]
  const float* w_attn = (const float*)d_in[1];  // [1024,3072]
  const float* b_attn = (const float*)d_in[2];  // [3072]
  const float* w_proj = (const float*)d_in[3];  // [1024,1024]
  const float* b_proj = (const float*)d_in[4];  // [1024]
  float* out = (float*)d_out;                   // [4,2048,1024] f32

  char* ws = (char*)d_ws;
  u16* qkbuf = (u16*)(ws);                   // 33,554,432 B
  u16* vtbuf = (u16*)(ws + 33554432);        // 16,777,216 B
  u16* xbf   = (u16*)(ws + 50331648);        // 16,777,216 B (reused as attn after QKV)
  u16* attnb = (u16*)(ws + 50331648);
  u16* wtA   = (u16*)(ws + 67108864);        //  6,291,456 B
  u16* wtP   = (u16*)(ws + 73400320);        //  2,097,152 B

  conv_kernel<<<4096, 256, 0, stream>>>(x, xbf);
  transpose_conv_kernel<<<dim3(3072 / 32, 1024 / 32), dim3(32, 8), 0, stream>>>(w_attn, wtA, 1024, 3072);
  transpose_conv_kernel<<<dim3(1024 / 32, 1024 / 32), dim3(32, 8), 0, stream>>>(w_proj, wtP, 1024, 1024);

  // QKV GEMM: xbf[8192,1024] @ w_attn^T -> qk (Q pre-scaled) + vT   (BN=256)
  gemm256_kernel<4, true><<<dim3(3072 / 256, 8192 / 256), 512, 0, stream>>>(
      xbf, wtA, b_attn, qkbuf, vtbuf, 8192, 3072, 1024);

  // flash attention
  flash_kernel<<<dim3(8, 64), 256, 0, stream>>>(qkbuf, vtbuf, attnb);

  // output projection (BN=128 -> 256 blocks, full GPU)
  gemm256_kernel<2, false><<<dim3(1024 / 128, 8192 / 256), 512, 0, stream>>>(
      attnb, wtP, b_proj, out, nullptr, 8192, 1024, 1024);
}

// Round 8
// 177.923 us; speedup vs baseline: 1.0621x; 1.0621x over previous
//
#include <hip/hip_runtime.h>

// CasualSelfAttention fused block for MI355X (gfx950).
// B=4, T=2048, C=1024, H=16, D=64.
// x->bf16 conv -> weight transpose+conv -> 2-phase dbuf 128x128 QKV GEMM (Q pre-scaled,
// V written transposed) -> 32x32-MFMA flash attention (in-register softmax) -> proj GEMM.
// Workspace (75,497,472 B):
//   [0,        33554432)  qk  bf16 [B,T,2C]      (Q cols 0..1023 pre-scaled, K cols 1024..2047)
//   [33554432, 50331648)  vT  bf16 [B*H][64][T]
//   [50331648, 67108864)  xbf bf16 [B,T,C]  (QKV phase)  /  attn bf16 [B,T,C] (flash+proj phase)
//   [67108864, 73400320)  w_attn^T bf16 [3C][C]
//   [73400320, 75497472)  w_proj^T bf16 [C][C]

using u16 = unsigned short;
using u32 = unsigned int;
using bf16x8 = __attribute__((ext_vector_type(8))) __bf16;
using f32x4  = __attribute__((ext_vector_type(4))) float;
using f32x16 = __attribute__((ext_vector_type(16))) float;
using u16x8  = __attribute__((ext_vector_type(8))) u16;
using u16x4  = __attribute__((ext_vector_type(4))) u16;
using u32x2  = __attribute__((ext_vector_type(2))) u32;
using u32x4  = __attribute__((ext_vector_type(4))) u32;
using fvec4  = __attribute__((ext_vector_type(4))) float;

__device__ __forceinline__ u16 f2bf(float f) {
  u32 u = __builtin_bit_cast(u32, f);
  u32 r = (u + 0x7FFFu + ((u >> 16) & 1u)) >> 16;
  return (u16)r;
}

__device__ __forceinline__ u32 cvtpk(float lo, float hi) {
  u32 r;
  asm("v_cvt_pk_bf16_f32 %0, %1, %2" : "=v"(r) : "v"(lo), "v"(hi));
  return r;
}

__device__ __forceinline__ f32x4 mfma16(bf16x8 a, bf16x8 b, f32x4 c) {
  return __builtin_amdgcn_mfma_f32_16x16x32_bf16(a, b, c, 0, 0, 0);
}

__device__ __forceinline__ f32x16 mfma32(bf16x8 a, bf16x8 b, f32x16 c) {
  return __builtin_amdgcn_mfma_f32_32x32x16_bf16(a, b, c, 0, 0, 0);
}

__device__ __forceinline__ void gld16(const u16* g, u16* l) {
  __builtin_amdgcn_global_load_lds(
      (const __attribute__((address_space(1))) void*)g,
      (__attribute__((address_space(3))) void*)l, 16, 0, 0);
}

// lgkm-only workgroup barrier: does NOT drain vmcnt
__device__ __forceinline__ void lgkm_barrier() {
  asm volatile("s_waitcnt lgkmcnt(0)" ::: "memory");
  __builtin_amdgcn_s_barrier();
  __builtin_amdgcn_sched_barrier(0);
}

// ---------------- f32 -> bf16 bulk convert ----------------
__global__ __launch_bounds__(256) void conv_kernel(
    const float* __restrict__ in, u16* __restrict__ out) {
  const size_t i = ((size_t)blockIdx.x * 256 + threadIdx.x) * 8;
  fvec4 a = *(const fvec4*)(in + i);
  fvec4 b = *(const fvec4*)(in + i + 4);
  u16x8 h;
#pragma unroll
  for (int j = 0; j < 4; ++j) { h[j] = f2bf(a[j]); h[4 + j] = f2bf(b[j]); }
  *(u16x8*)(out + i) = h;
}

// ---------------- transpose + f32->bf16 convert: W[K][N] -> Wt[N][K] ----------------
__global__ __launch_bounds__(256) void transpose_conv_kernel(
    const float* __restrict__ W, u16* __restrict__ Wt, int K, int N) {
  __shared__ float tile[32][33];
  const int n0 = blockIdx.x * 32, k0 = blockIdx.y * 32;
  const int tx = threadIdx.x, ty = threadIdx.y;  // 32 x 8
#pragma unroll
  for (int j = 0; j < 4; ++j)
    tile[ty + j * 8][tx] = W[(size_t)(k0 + ty + j * 8) * N + n0 + tx];
  __syncthreads();
#pragma unroll
  for (int j = 0; j < 4; ++j)
    Wt[(size_t)(n0 + ty + j * 8) * K + k0 + tx] = f2bf(tile[tx][ty + j * 8]);
}

// ---------------- 128x128x32 2-phase dbuf bf16 GEMM ----------------
// 256 threads = 4 waves (2x2), per-wave C tile 64x64, acc[4][4].
// LDS 32 KiB (2 dbuf x (A 8KB + B 8KB)) -> ~4 blocks/CU resident: stalls hidden
// by co-resident blocks. Per iter: stage next tile FIRST (4x global_load_lds),
// ds_read 8 frags, lgkmcnt(0), 16 MFMA, counted vmcnt, barrier.
// Zero-conflict layout: 64B row-slices, 16B slot ^= (row>>1)&3 on source AND read.
template <bool QKV>
__global__ __launch_bounds__(256) void gemm_kernel(
    const u16* __restrict__ A, const u16* __restrict__ Bt,
    const float* __restrict__ bias, void* __restrict__ Cp,
    u16* __restrict__ vt, int M, int N, int K) {
  constexpr float SC = 0.18033688011112042f;  // 0.125 * log2(e)
  __shared__ u16 As[2][4096];
  __shared__ u16 Bs[2][4096];
  const int tid = threadIdx.x;
  const int l = tid & 63, w = tid >> 6;
  const int l15 = l & 15, l16 = l >> 4;
  const int wm = (w >> 1) * 64, wn = (w & 1) * 64;

  // XCD-aware chunked swizzle (nwg % 8 == 0 for all our grids)
  const u32 nwg = gridDim.x * gridDim.y;
  u32 f = blockIdx.y * gridDim.x + blockIdx.x;
  f = (f & 7) * (nwg >> 3) + (f >> 3);
  const long mbase = (long)(f / gridDim.x) * 128;
  const long nbase = (long)(f % gridDim.x) * 128;

  // staging: rows tid>>2 and tid>>2 + 64; source 16B slot pre-swizzled
  const int srow = tid >> 2;
  const int scol = ((tid & 3) ^ ((srow >> 1) & 3)) * 8;  // (srow+64)>>1 &3 == (srow>>1)&3
  const u16* gA0 = A + (mbase + srow) * (long)K + scol;
  const u16* gA1 = gA0 + 64 * (long)K;
  const u16* gB0 = Bt + (nbase + srow) * (long)K + scol;
  const u16* gB1 = gB0 + 64 * (long)K;

  f32x4 acc[4][4] = {};
  const int NT = K >> 5;

#define STAGE(buf, koff)                         \
  gld16(gA0 + (koff), &As[buf][tid * 8]);        \
  gld16(gA1 + (koff), &As[buf][tid * 8 + 2048]); \
  gld16(gB0 + (koff), &Bs[buf][tid * 8]);        \
  gld16(gB1 + (koff), &Bs[buf][tid * 8 + 2048]);

  STAGE(0, 0);
  asm volatile("s_waitcnt vmcnt(0)" ::: "memory");
  __builtin_amdgcn_s_barrier();

  for (int t = 0; t < NT; ++t) {
    const int cur = t & 1;
    if (t + 1 < NT) { STAGE(cur ^ 1, (t + 1) * 32); }  // issue-early: lands under MFMA

    bf16x8 af[4], bfr[4];
#pragma unroll
    for (int i = 0; i < 4; ++i) {
      const int row = wm + i * 16 + l15;
      af[i] = *(const bf16x8*)(&As[cur][row * 32 + ((l16 ^ ((row >> 1) & 3)) * 8)]);
    }
#pragma unroll
    for (int j = 0; j < 4; ++j) {
      const int row = wn + j * 16 + l15;
      bfr[j] = *(const bf16x8*)(&Bs[cur][row * 32 + ((l16 ^ ((row >> 1) & 3)) * 8)]);
    }
    asm volatile("s_waitcnt lgkmcnt(0)" ::: "memory");
    __builtin_amdgcn_sched_barrier(0);
    __builtin_amdgcn_s_setprio(1);
#pragma unroll
    for (int i = 0; i < 4; ++i)
#pragma unroll
      for (int j = 0; j < 4; ++j)
        acc[i][j] = mfma16(af[i], bfr[j], acc[i][j]);
    __builtin_amdgcn_s_setprio(0);
    __builtin_amdgcn_sched_barrier(0);
    if (t + 1 < NT) { asm volatile("s_waitcnt vmcnt(0)" ::: "memory"); }
    __builtin_amdgcn_s_barrier();
  }
#undef STAGE

  if constexpr (QKV) {
    const bool isv = (nbase >= 2048);
#pragma unroll
    for (int i = 0; i < 4; ++i) {
#pragma unroll
      for (int j = 0; j < 4; ++j) {
        const long m0 = mbase + wm + i * 16 + l16 * 4;
        const int n = (int)nbase + wn + j * 16 + l15;
        const float bv = bias[n];
        if (!isv) {
          u16* qkp = (u16*)Cp;
          const float sc = (n < 1024) ? SC : 1.0f;
#pragma unroll
          for (int r = 0; r < 4; ++r)
            qkp[(m0 + r) * 2048 + n] = f2bf((acc[i][j][r] + bv) * sc);
        } else {
          const int vc = n - 2048, hh = vc >> 6, dd = vc & 63;
          const int bb = (int)(m0 >> 11), t0 = (int)(m0 & 2047);
          u16x4 pk;
#pragma unroll
          for (int r = 0; r < 4; ++r) pk[r] = f2bf(acc[i][j][r] + bv);
          *(u16x4*)(vt + ((size_t)(bb * 16 + hh) * 64 + dd) * 2048 + t0) = pk;
        }
      }
    }
  } else {
#pragma unroll
    for (int i = 0; i < 4; ++i) {
#pragma unroll
      for (int j = 0; j < 4; ++j) {
        const long row0 = mbase + wm + i * 16 + l16 * 4;
        const long col = nbase + wn + j * 16 + l15;
        const float bv = bias[col];
#pragma unroll
        for (int r = 0; r < 4; ++r)
          ((float*)Cp)[(row0 + r) * (long)N + col] = acc[i][j][r] + bv;
      }
    }
  }
}

// ---------------- 32x32-MFMA flash attention, in-register softmax ----------------
// grid 512 (8 pairs x 64 bh); block = 4 waves x 32 q (QBLK=128); paired {p,15-p}: 34 iters.
// Swapped QK^T at 32x32: C col = q (lane&31), row = key crow(r,hi)=(r&3)+8*(r>>2)+4*hi.
// P redistribution to the PV B-fragment = 16 cvt_pk + 8 v_permlane32_swap (no LDS).
// K/V double-buffered (1 barrier/iter); fixed-shift softmax p=exp2(s-4).
__global__ __launch_bounds__(256, 2) void flash_kernel(
    const u16* __restrict__ qk, const u16* __restrict__ vt, u16* __restrict__ attn_out) {
  constexpr float MFIX = 4.0f;
  __shared__ u16 Ks[2][64 * 64];  // [buf][key][64 d], XOR-swizzled 128B rows
  __shared__ u16 Vs[2][64 * 64];  // [buf][d][64 key]
  const int tid = threadIdx.x;
  const int lane = tid & 63, w = tid >> 6;
  const int l31 = lane & 31, hi = lane >> 5;
  const int xorv = (l31 & 7) << 4;

  const u32 i = blockIdx.y * 8 + blockIdx.x;
  const int jj = i >> 3;
  const int bh = (i & 7) | ((jj & 7) << 3);
  const int pair = (int)(i >> 6);
  const int b = bh >> 4, h = bh & 15;
  const u16* qbase = qk + (size_t)b * 2048 * 2048 + h * 64;
  const u16* kbase = qbase + 1024;
  const u16* vbase = vt + (size_t)bh * 64 * 2048;
  u16* obase = attn_out + (size_t)b * 2048 * 1024 + h * 64;

  const int r0 = tid >> 3, c0 = (tid & 7) * 8;
  const int sco = ((c0 * 2) ^ ((r0 & 7) << 4)) >> 1;  // swizzled staging col (u16)

  int cur = 0;
  for (int half = 0; half < 2; ++half) {
    const int qt = half ? (15 - pair) : pair;
    const int nt = 2 * qt + 2;
    const int qr0 = qt * 128 + w * 32;
    const int q = qr0 + l31;

    // Q B-frags: col=q, k(d) = ds*16 + hi*8 + e
    bf16x8 qf[4];
#pragma unroll
    for (int ds = 0; ds < 4; ++ds)
      qf[ds] = *(const bf16x8*)(qbase + (size_t)q * 2048 + ds * 16 + hi * 8);

    f32x16 oacc[2] = {};
    float lsum = 0.f;

    u16x8 kreg[2], vreg[2];
    kreg[0] = *(const u16x8*)(kbase + (size_t)r0 * 2048 + c0);
    kreg[1] = *(const u16x8*)(kbase + (size_t)(r0 + 32) * 2048 + c0);
    vreg[0] = *(const u16x8*)(vbase + (size_t)r0 * 2048 + c0);
    vreg[1] = *(const u16x8*)(vbase + (size_t)(r0 + 32) * 2048 + c0);

    for (int kt = 0; kt < nt; ++kt) {
      const int kb = kt * 64;
      // stage into buf[cur] (other waves' reads of buf[cur^1] unaffected)
      *(u16x8*)(&Ks[cur][r0 * 64 + sco]) = kreg[0];
      *(u16x8*)(&Ks[cur][(r0 + 32) * 64 + sco]) = kreg[1];
      *(u16x8*)(&Vs[cur][r0 * 64 + sco]) = vreg[0];
      *(u16x8*)(&Vs[cur][(r0 + 32) * 64 + sco]) = vreg[1];
      lgkm_barrier();  // all writes visible; vmcnt NOT drained
      if (kt + 1 < nt) {  // prefetch next tile
        const int nb = kb + 64;
        kreg[0] = *(const u16x8*)(kbase + (size_t)(nb + r0) * 2048 + c0);
        kreg[1] = *(const u16x8*)(kbase + (size_t)(nb + r0 + 32) * 2048 + c0);
        vreg[0] = *(const u16x8*)(vbase + (size_t)r0 * 2048 + nb + c0);
        vreg[1] = *(const u16x8*)(vbase + (size_t)(r0 + 32) * 2048 + nb + c0);
      }

      // S^T = K Q^T (two 32-key halves), A = K rows from LDS
      f32x16 s0 = {}, s1 = {};
      __builtin_amdgcn_s_setprio(1);
#pragma unroll
      for (int ds = 0; ds < 4; ++ds) {
        const int col = (ds * 32 + hi * 16) ^ xorv;
        bf16x8 k0 = *(const bf16x8*)((const char*)&Ks[cur][0] + l31 * 128 + col);
        bf16x8 k1 = *(const bf16x8*)((const char*)&Ks[cur][0] + (32 + l31) * 128 + col);
        s0 = mfma32(k0, qf[ds], s0);
        s1 = mfma32(k1, qf[ds], s1);
      }
      __builtin_amdgcn_s_setprio(0);

      if (kb + 63 > qr0) {  // causal mask (tiles crossing this wave's diagonal)
#pragma unroll
        for (int r = 0; r < 16; ++r) {
          const int crow = (r & 3) + 8 * (r >> 2) + 4 * hi;
          if (kb + crow > q) s0[r] = -1e30f;
          if (kb + 32 + crow > q) s1[r] = -1e30f;
        }
      }

      // p = exp2(s - MFIX), per-lane lsum, pack to PV B-frags in-register
      float p0[16], p1[16];
      float ps = 0.f;
#pragma unroll
      for (int r = 0; r < 16; ++r) {
        p0[r] = exp2f(s0[r] - MFIX);
        p1[r] = exp2f(s1[r] - MFIX);
        ps += p0[r] + p1[r];
      }
      lsum += ps;

      bf16x8 pf[4];  // B-frag per 16-key slice: col=q, k=key (l>>5)*8+e
#pragma unroll
      for (int kh = 0; kh < 2; ++kh) {
#pragma unroll
        for (int c = 0; c < 2; ++c) {
          const float* pp = kh ? p1 : p0;
          const int bs = c * 8;
          u32 L0 = cvtpk(pp[bs + 0], pp[bs + 1]);
          u32 L1 = cvtpk(pp[bs + 2], pp[bs + 3]);
          u32 L2 = cvtpk(pp[bs + 4], pp[bs + 5]);
          u32 L3 = cvtpk(pp[bs + 6], pp[bs + 7]);
          asm("v_permlane32_swap_b32 %0, %1" : "+v"(L0), "+v"(L2));
          asm("v_permlane32_swap_b32 %0, %1" : "+v"(L1), "+v"(L3));
          u32x4 pk = {L0, L1, L2, L3};
          pf[kh * 2 + c] = __builtin_bit_cast(bf16x8, pk);
        }
      }

      // O^T += V^T P : A = V^T rows (d) from LDS, B = pf
      __builtin_amdgcn_s_setprio(1);
#pragma unroll
      for (int dh = 0; dh < 2; ++dh) {
#pragma unroll
        for (int ks = 0; ks < 4; ++ks) {
          const int col = (ks * 32 + hi * 16) ^ xorv;
          bf16x8 vf = *(const bf16x8*)((const char*)&Vs[cur][0] + (dh * 32 + l31) * 128 + col);
          oacc[dh] = mfma32(vf, pf[ks], oacc[dh]);
        }
      }
      __builtin_amdgcn_s_setprio(0);
      cur ^= 1;
    }

    // epilogue: full row-sum (partner holds other 32 keys), lane-local normalize
    lsum += __shfl_xor(lsum, 32);
    const float inv = 1.0f / lsum;
    u16* orow = obase + (size_t)q * 1024;
#pragma unroll
    for (int dh = 0; dh < 2; ++dh) {
#pragma unroll
      for (int jq = 0; jq < 4; ++jq) {  // d quad: dh*32 + 8*jq + 4*hi + 0..3
        u32x2 pk;
        pk[0] = cvtpk(oacc[dh][jq * 4 + 0] * inv, oacc[dh][jq * 4 + 1] * inv);
        pk[1] = cvtpk(oacc[dh][jq * 4 + 2] * inv, oacc[dh][jq * 4 + 3] * inv);
        *(u32x2*)(orow + dh * 32 + 8 * jq + 4 * hi) = pk;
      }
    }
  }
}

extern "C" void kernel_launch(void* const* d_in, const int* in_sizes, int n_in,
                              void* d_out, int out_size, void* d_ws, size_t ws_size,
                              hipStream_t stream) {
  (void)in_sizes; (void)n_in; (void)out_size; (void)ws_size;
  const float* x      = (const float*)d_in[0];  // [4,2048,1024]
  const float* w_attn = (const float*)d_in[1];  // [1024,3072]
  const float* b_attn = (const float*)d_in[2];  // [3072]
  const float* w_proj = (const float*)d_in[3];  // [1024,1024]
  const float* b_proj = (const float*)d_in[4];  // [1024]
  float* out = (float*)d_out;                   // [4,2048,1024] f32

  char* ws = (char*)d_ws;
  u16* qkbuf = (u16*)(ws);                   // 33,554,432 B
  u16* vtbuf = (u16*)(ws + 33554432);        // 16,777,216 B
  u16* xbf   = (u16*)(ws + 50331648);        // 16,777,216 B (reused as attn after QKV)
  u16* attnb = (u16*)(ws + 50331648);
  u16* wtA   = (u16*)(ws + 67108864);        //  6,291,456 B
  u16* wtP   = (u16*)(ws + 73400320);        //  2,097,152 B

  conv_kernel<<<4096, 256, 0, stream>>>(x, xbf);
  transpose_conv_kernel<<<dim3(3072 / 32, 1024 / 32), dim3(32, 8), 0, stream>>>(w_attn, wtA, 1024, 3072);
  transpose_conv_kernel<<<dim3(1024 / 32, 1024 / 32), dim3(32, 8), 0, stream>>>(w_proj, wtP, 1024, 1024);

  // QKV GEMM: xbf[8192,1024] @ w_attn^T -> qk (Q pre-scaled) + vT
  gemm_kernel<true><<<dim3(3072 / 128, 8192 / 128), 256, 0, stream>>>(
      xbf, wtA, b_attn, qkbuf, vtbuf, 8192, 3072, 1024);

  // flash attention
  flash_kernel<<<dim3(8, 64), 256, 0, stream>>>(qkbuf, vtbuf, attnb);

  // output projection
  gemm_kernel<false><<<dim3(1024 / 128, 8192 / 128), 256, 0, stream>>>(
      attnb, wtP, b_proj, out, nullptr, 8192, 1024, 1024);
}